// Round 9
// baseline (800.502 us; speedup 1.0000x reference)
//
#include <hip/hip_runtime.h>
#include <hip/hip_cooperative_groups.h>
#include <hip/hip_bf16.h>
#include <math.h>

#define C_DIM 1024
#define QKS  2048    // Q|K row stride in bf16 workspace

namespace cg = cooperative_groups;

typedef __attribute__((ext_vector_type(8))) short bf16x8;   // 8 bf16 = 4 VGPRs
typedef __attribute__((ext_vector_type(4))) float f32x4;    // MFMA C/D

__device__ __forceinline__ unsigned short f2bf(float f) {
  __hip_bfloat16 h = __float2bfloat16(f);
  return *(reinterpret_cast<unsigned short*>(&h));
}
__device__ __forceinline__ float bf2f(unsigned short u) {
  return __uint_as_float(((unsigned int)u) << 16);
}
__device__ __forceinline__ f32x4 mfma16(bf16x8 a, bf16x8 b, f32x4 c) {
  return __builtin_amdgcn_mfma_f32_16x16x32_bf16(a, b, c, 0, 0, 0);
}
__device__ __forceinline__ void gload_lds16(const unsigned short* g,
                                            unsigned short* l) {
  __builtin_amdgcn_global_load_lds(
      (const __attribute__((address_space(1))) void*)(g),
      (__attribute__((address_space(3))) void*)(l), 16, 0, 0);
}

// rowsum[r] parked in never-used cells of P (128-tile granularity):
//   r <  T-128: P[r][T-2..T)  (row r uses cols < ceil128(r+1) <= T-128)
//   r >= T-128: P[0][256 + 2*(r-(T-128)))  (row 0 uses cols < 128 only;
//               cols [256,512) of row 0 are read by nobody: PV row-block 0
//               has kend=128). 4-byte aligned. Zeroed after QKV (slots
//               overlap xb/WT bytes), before S.
__device__ __forceinline__ float* rs_addr(unsigned short* P, int r, int T) {
  return (r < T - 128)
      ? (float*)(P + (size_t)r * T + (T - 2))
      : (float*)(P + 256 + ((r - (T - 128)) << 1));
}

// ---------------------------------------------------------------------------
// gemm_tile<MODE>: one 128x128 output tile, BK=32, 4 waves (wave w owns cols
// [w*32,w*32+32) x all 128 rows: 8 m-frags x 2 n-frags). 2-phase dbuf with
// global_load_lds (32 KB LDS): barrier (drains prev stage) -> stage(t+1) ->
// ds_read + 16 MFMA. NT = (kend-kbeg)/32, always even here -> cross-tile
// buffer reuse race-free (final reads hit buf1; next prologue writes buf0,
// whose last reads drained at the final loop-top barrier).
// MODE 4: bf16 out + bias (col, or row if rowbias)          (QKV)
// MODE 2: P' = exp(mask(s/32)) unnormalized bf16 + rowsum atomics (S+softmax)
// MODE 3: fp32 out scaled by 1/rowsum, optional atomicAdd   (PV split-K)
// ---------------------------------------------------------------------------
template <int MODE>
__device__ void gemm_tile(
    const unsigned short* A, const unsigned short* BT, void* Cv,
    const float* bias, int lda, int ldb, int ldc, int T, int np,
    int m0, int n0, int kbeg, int kend, bool use_atomic, bool rowbias,
    unsigned short (*As)[128][32], unsigned short (*Bs)[128][32],
    unsigned short* Prs) {
  const int tid = threadIdx.x, lane = tid & 63, w = tid >> 6;
  const int qd = lane >> 4, n16 = lane & 15;

  f32x4 s[8][2];
#pragma unroll
  for (int mt = 0; mt < 8; ++mt)
#pragma unroll
    for (int j = 0; j < 2; ++j) s[mt][j] = (f32x4){0.f, 0.f, 0.f, 0.f};

  // staging map: lane -> (row in 16-row chunk = lane>>2, 16B k-unit = lane&3)
  const int srow = lane >> 2;
  const int skc  = (lane & 3) << 3;
  const unsigned short* ag0 = A  + (size_t)(m0 + (w << 5) + srow) * lda + kbeg + skc;
  const unsigned short* ag1 = ag0 + (size_t)16 * lda;
  const unsigned short* bg0 = BT + (size_t)(n0 + (w << 5) + srow) * ldb + kbeg + skc;
  const unsigned short* bg1 = bg0 + (size_t)16 * ldb;

  const int nt = (kend - kbeg) >> 5;   // even, >= 4 for all call sites

  gload_lds16(ag0, &As[0][(w << 5)][0]);
  gload_lds16(ag1, &As[0][(w << 5) + 16][0]);
  gload_lds16(bg0, &Bs[0][(w << 5)][0]);
  gload_lds16(bg1, &Bs[0][(w << 5) + 16][0]);

  int cur = 0;
  for (int t = 0; t < nt; ++t) {
    __syncthreads();   // drains stage(t) [implicit vmcnt(0)]; protects reuse
    if (t + 1 < nt) {
      const int ko = (t + 1) << 5;
      const int nbuf = cur ^ 1;
      gload_lds16(ag0 + ko, &As[nbuf][(w << 5)][0]);
      gload_lds16(ag1 + ko, &As[nbuf][(w << 5) + 16][0]);
      gload_lds16(bg0 + ko, &Bs[nbuf][(w << 5)][0]);
      gload_lds16(bg1 + ko, &Bs[nbuf][(w << 5) + 16][0]);
    }
    bf16x8 bf0 = *(const bf16x8*)&Bs[cur][(w << 5) + n16][qd << 3];
    bf16x8 bf1 = *(const bf16x8*)&Bs[cur][(w << 5) + 16 + n16][qd << 3];
#pragma unroll
    for (int mt = 0; mt < 8; ++mt) {
      bf16x8 af = *(const bf16x8*)&As[cur][(mt << 4) + n16][qd << 3];
      s[mt][0] = mfma16(af, bf0, s[mt][0]);
      s[mt][1] = mfma16(af, bf1, s[mt][1]);
    }
    cur ^= 1;
  }

  // ---- epilogues. Frag map: col = n16, row = qd*4 + r within each 16x16.
  if (MODE == 4) {
    unsigned short* Cb = (unsigned short*)Cv;
#pragma unroll
    for (int mt = 0; mt < 8; ++mt)
#pragma unroll
      for (int j = 0; j < 2; ++j) {
        const int col = n0 + (w << 5) + (j << 4) + n16;
        const float bc = rowbias ? 0.f : bias[col];
#pragma unroll
        for (int r = 0; r < 4; ++r) {
          const int row = m0 + (mt << 4) + (qd << 2) + r;
          const float v = s[mt][j][r] + (rowbias ? bias[row] : bc);
          Cb[(size_t)row * ldc + col] = f2bf(v);
        }
      }
  } else if (MODE == 2) {
    // unnormalized exp + per-row sum atomics (|s/32| ~ N(0,1): overflow-safe)
    unsigned short* Cb = (unsigned short*)Cv;
#pragma unroll
    for (int mt = 0; mt < 8; ++mt) {
      const int rowb = m0 + (mt << 4) + (qd << 2);
      float rsum[4] = {0.f, 0.f, 0.f, 0.f};
#pragma unroll
      for (int j = 0; j < 2; ++j) {
        const int col = n0 + (w << 5) + (j << 4) + n16;
#pragma unroll
        for (int r = 0; r < 4; ++r) {
          const int row = rowb + r;
          float p = 0.f;
          if (col <= row && col >= np && row >= np)
            p = __expf(s[mt][j][r] * 0.03125f);
          Cb[(size_t)row * ldc + col] = f2bf(p);
          rsum[r] += p;
        }
      }
#pragma unroll
      for (int r = 0; r < 4; ++r) {   // reduce over the 16 col-lanes (n16)
        rsum[r] += __shfl_xor(rsum[r], 1);
        rsum[r] += __shfl_xor(rsum[r], 2);
        rsum[r] += __shfl_xor(rsum[r], 4);
        rsum[r] += __shfl_xor(rsum[r], 8);
      }
      if (n16 == 0) {
#pragma unroll
        for (int r = 0; r < 4; ++r)
          atomicAdd(rs_addr(Prs, rowb + r, T), rsum[r]);
      }
    }
  } else {  // MODE 3
    float* Cf = (float*)Cv;
#pragma unroll
    for (int mt = 0; mt < 8; ++mt) {
      const int rowb = m0 + (mt << 4) + (qd << 2);
      float inv[4];
#pragma unroll
      for (int r = 0; r < 4; ++r)
        inv[r] = 1.0f / fmaxf(*rs_addr(Prs, rowb + r, T), 1e-37f);
#pragma unroll
      for (int j = 0; j < 2; ++j) {
        const int col = n0 + (w << 5) + (j << 4) + n16;
#pragma unroll
        for (int r = 0; r < 4; ++r) {
          const float v = s[mt][j][r] * inv[r];
          if (use_atomic) atomicAdd(&Cf[(size_t)(rowb + r) * ldc + col], v);
          else            Cf[(size_t)(rowb + r) * ldc + col] = v;
        }
      }
    }
  }
}

// ---------------------------------------------------------------------------
// attn_all: the whole pipeline as phases of ONE (cooperative) kernel.
//   ph0: cast x->xb bf16, zero out[1024:], transpose W->WT
//   ph1: QKV  (grid-stride over (T/128)*16 QK tiles + 8*(T/128) V tiles)
//   ph2: zero rowsum slots (must be between QKV and S: slots overlap xb/WT)
//   ph3: S    (lower-tri tiles; fused exp + rowsum atomics)
//   ph4: PV   (causal split-K chunks of 1024; scale by 1/rowsum)
//   ph5: padfix (rows < n_padd := mean of V; no-op when n_padd == 0)
// grid.sync() (+ __threadfence) between phases. plo/phi select a phase range
// so the same kernel works as 6 sequential normal launches if cooperative
// launch is unavailable (syncs are skipped when plo == phi).
// ---------------------------------------------------------------------------
__global__ __launch_bounds__(256, 4) void attn_all(
    const float* x, const float* W, const float* b, const int* np_p,
    float* out, unsigned short* ws, int T, int plo, int phi) {
  __shared__ __align__(16) unsigned char smem[32768];
  unsigned short (*As)[128][32] = (unsigned short(*)[128][32])smem;
  unsigned short (*Bs)[128][32] = (unsigned short(*)[128][32])(smem + 16384);

  unsigned short* qkb = ws;
  unsigned short* vtb = qkb + (size_t)T * QKS;
  unsigned short* xb  = vtb + (size_t)C_DIM * T;
  unsigned short* WT  = xb  + (size_t)T * C_DIM;
  unsigned short* P   = xb;

  const int nb = (int)gridDim.x, bid = (int)blockIdx.x, tid = threadIdx.x;
  const int g = bid * 256 + tid, nthr = nb * 256;
  const int tq = T >> 7;

  for (int ph = plo; ph <= phi; ++ph) {
    if (ph == 0) {
      // cast x -> xb (float4 -> ushort4)
      const int n4 = (T * C_DIM) >> 2;
      for (int i = g; i < n4; i += nthr) {
        float4 v = *(const float4*)(x + ((size_t)i << 2));
        ushort4 u;
        u.x = f2bf(v.x); u.y = f2bf(v.y); u.z = f2bf(v.z); u.w = f2bf(v.w);
        *(ushort4*)(xb + ((size_t)i << 2)) = u;
      }
      // zero out rows [1024, T)  (PV atomic-target region)
      const int nz4 = ((T - C_DIM) * C_DIM) >> 2;
      const float4 z = {0.f, 0.f, 0.f, 0.f};
      for (int i = g; i < nz4; i += nthr)
        *(float4*)(out + (size_t)C_DIM * C_DIM + ((size_t)i << 2)) = z;
      // transpose W [1024][3072] -> WT [3072][1024] bf16, 64x64 tiles
      float (*Ls)[65] = (float(*)[65])smem;
      const int c = (tid & 15) << 2, r = tid >> 4;
      for (int tI = bid; tI < 768; tI += nb) {
        const int n0 = (tI % 48) << 6, k0 = (tI / 48) << 6;
        __syncthreads();   // protect Ls reuse across loop iterations
#pragma unroll
        for (int rr = 0; rr < 64; rr += 16) {
          float4 v = *(const float4*)(W + (size_t)(k0 + r + rr) * 3072 + n0 + c);
          Ls[r + rr][c + 0] = v.x; Ls[r + rr][c + 1] = v.y;
          Ls[r + rr][c + 2] = v.z; Ls[r + rr][c + 3] = v.w;
        }
        __syncthreads();
#pragma unroll
        for (int rr = 0; rr < 64; rr += 16) {
          const int X = r + rr;
          ushort4 u;
          u.x = f2bf(Ls[c + 0][X]); u.y = f2bf(Ls[c + 1][X]);
          u.z = f2bf(Ls[c + 2][X]); u.w = f2bf(Ls[c + 3][X]);
          *(ushort4*)(WT + (size_t)(n0 + X) * C_DIM + k0 + c) = u;
        }
      }
    } else if (ph == 1) {
      // QKV: QK tiles then V^T tiles
      const int nQKx = QKS >> 7;            // 16
      const int nQK  = tq * nQKx;
      const int nTot = nQK + (C_DIM >> 7) * tq;
      for (int id = bid; id < nTot; id += nb) {
        if (id < nQK) {
          gemm_tile<4>(xb, WT, qkb, b, C_DIM, C_DIM, QKS, T, 0,
                       (id / nQKx) << 7, (id % nQKx) << 7, 0, C_DIM,
                       false, false, As, Bs, (unsigned short*)0);
        } else {
          const int iv = id - nQK;
          gemm_tile<4>(WT + (size_t)QKS * C_DIM, xb, vtb, b + QKS,
                       C_DIM, C_DIM, T, T, 0,
                       (iv / tq) << 7, (iv % tq) << 7, 0, C_DIM,
                       false, true, As, Bs, (unsigned short*)0);
        }
      }
    } else if (ph == 2) {
      for (int r2 = g; r2 < T; r2 += nthr) *rs_addr(P, r2, T) = 0.f;
    } else if (ph == 3) {
      const int np = *np_p;
      const int ntri = tq * (tq + 1) / 2;
      for (int id = bid; id < ntri; id += nb) {
        int by = (int)((sqrtf((float)(8 * id + 1)) - 1.0f) * 0.5f);
        while ((by + 1) * (by + 2) / 2 <= id) ++by;
        while (by * (by + 1) / 2 > id) --by;
        const int bx = id - by * (by + 1) / 2;
        gemm_tile<2>(qkb, qkb + C_DIM, P, b, QKS, QKS, T, T, np,
                     by << 7, bx << 7, 0, C_DIM, false, false, As, Bs, P);
      }
    } else if (ph == 4) {
      int tot = 0;
      for (int bi = 0; bi < tq; ++bi) tot += (bi >> 3) + 1;
      tot <<= 3;                            // x 8 col-tiles
      for (int id = bid; id < tot; id += nb) {
        int rem = id, bi = 0;
        while (rem >= (((bi >> 3) + 1) << 3)) { rem -= ((bi >> 3) + 1) << 3; ++bi; }
        const int sK = rem >> 3, nx = rem & 7;
        const int kfull = (bi + 1) << 7;
        const int kbeg = sK << 10;
        const int kend = (kbeg + 1024 < kfull) ? kbeg + 1024 : kfull;
        gemm_tile<3>(P, vtb, out, b, T, T, C_DIM, T, 0,
                     bi << 7, nx << 7, kbeg, kend, kfull > 1024, false,
                     As, Bs, P);
      }
    } else {  // ph == 5: padfix
      const int np = *np_p;
      for (int id = bid; id < (T >> 5); id += nb) {
        const int row0 = id << 5;
        if (row0 >= np) continue;
        const int pc = min(np - row0, 32);
        const int c4 = tid << 2;
        float a[4] = {0.f, 0.f, 0.f, 0.f};
#pragma unroll
        for (int cch = 0; cch < 4; ++cch) {
          const unsigned short* vr = vtb + (size_t)(c4 + cch) * T;
          for (int j = 0; j < T; j += 8) {
            uint4 v = *(const uint4*)(vr + j);
            a[cch] += bf2f(v.x & 0xffff) + bf2f(v.x >> 16)
                    + bf2f(v.y & 0xffff) + bf2f(v.y >> 16)
                    + bf2f(v.z & 0xffff) + bf2f(v.z >> 16)
                    + bf2f(v.w & 0xffff) + bf2f(v.w >> 16);
          }
        }
        const float inv = 1.0f / (float)T;
        float4 rv = {a[0] * inv, a[1] * inv, a[2] * inv, a[3] * inv};
        for (int r2 = 0; r2 < pc; ++r2)
          *(float4*)(out + (size_t)(row0 + r2) * C_DIM + c4) = rv;
      }
    }
    if (ph < phi) {       // inter-phase grid barrier (cooperative path only)
      __threadfence();
      cg::this_grid().sync();
    }
  }
}

// ---------------------------------------------------------------------------
extern "C" void kernel_launch(void* const* d_in, const int* in_sizes, int n_in,
                              void* d_out, int out_size, void* d_ws, size_t ws_size,
                              hipStream_t stream) {
  const float* x    = (const float*)d_in[0];
  const float* W    = (const float*)d_in[1];
  const float* b    = (const float*)d_in[2];
  const int* n_padd = (const int*)d_in[3];
  float* out = (float*)d_out;
  unsigned short* ws = (unsigned short*)d_ws;

  const int T = in_sizes[0] / C_DIM;

  static int s_grid = -1;
  if (s_grid < 0) {
    int mab = 0;
    hipOccupancyMaxActiveBlocksPerMultiprocessor(&mab, attn_all, 256, 0);
    hipDeviceProp_t prop;
    int dev = 0;
    hipGetDevice(&dev);
    hipGetDeviceProperties(&prop, dev);
    int gr = mab * prop.multiProcessorCount;
    if (gr < 256) gr = 256;
    if (gr > 1024) gr = 1024;
    s_grid = gr;
  }

  int Tl = T, plo = 0, phi = 5;
  void* args[] = {(void*)&x, (void*)&W, (void*)&b, (void*)&n_padd,
                  (void*)&out, (void*)&ws, (void*)&Tl, (void*)&plo, (void*)&phi};
  hipError_t e = hipLaunchCooperativeKernel((void*)attn_all, dim3(s_grid),
                                            dim3(256), args, 0, stream);
  if (e != hipSuccess) {
    // fallback: 6 sequential normal launches (grid.sync skipped: plo == phi)
    for (int ph = 0; ph <= 5; ++ph)
      attn_all<<<dim3(s_grid), dim3(256), 0, stream>>>(
          x, W, b, n_padd, out, ws, T, ph, ph);
  }
}

// Round 10
// 221.878 us; speedup vs baseline: 3.6079x; 3.6079x over previous
//
#include <hip/hip_runtime.h>
#include <hip/hip_bf16.h>
#include <math.h>

#define C_DIM 1024
#define QKS  2048    // Q|K row stride in bf16 workspace

typedef __attribute__((ext_vector_type(8))) short bf16x8;   // 8 bf16 = 4 VGPRs
typedef __attribute__((ext_vector_type(4))) float f32x4;    // MFMA C/D

__device__ __forceinline__ unsigned short f2bf(float f) {
  __hip_bfloat16 h = __float2bfloat16(f);
  return *(reinterpret_cast<unsigned short*>(&h));
}
__device__ __forceinline__ float bf2f(unsigned short u) {
  return __uint_as_float(((unsigned int)u) << 16);
}
__device__ __forceinline__ f32x4 mfma16(bf16x8 a, bf16x8 b, f32x4 c) {
  return __builtin_amdgcn_mfma_f32_16x16x32_bf16(a, b, c, 0, 0, 0);
}
__device__ __forceinline__ void gload_lds16(const unsigned short* g,
                                            unsigned short* l) {
  __builtin_amdgcn_global_load_lds(
      (const __attribute__((address_space(1))) void*)(g),
      (__attribute__((address_space(3))) void*)(l), 16, 0, 0);
}

#define VMCNT(n)  asm volatile("s_waitcnt vmcnt(" #n ")" ::: "memory")
#define LGKMCNT0  asm volatile("s_waitcnt lgkmcnt(0)" ::: "memory")
#define SBAR      __builtin_amdgcn_sched_barrier(0)
#define BARRIER   __builtin_amdgcn_s_barrier()

// ---------------------------------------------------------------------------
// Kernel 0a: cast x (fp32) -> xb (bf16)
// ---------------------------------------------------------------------------
__global__ __launch_bounds__(256) void cast_x(
    const float* __restrict__ x, unsigned short* __restrict__ xb) {
  const int i = (blockIdx.x * 256 + threadIdx.x) << 2;
  float4 v = *(const float4*)(x + i);
  ushort4 u;
  u.x = f2bf(v.x); u.y = f2bf(v.y); u.z = f2bf(v.z); u.w = f2bf(v.w);
  *(ushort4*)(xb + i) = u;
}

// ---------------------------------------------------------------------------
// Kernel 0b: W [1024][3072] fp32 -> WT [3072][1024] bf16
// ---------------------------------------------------------------------------
__global__ __launch_bounds__(256) void transpose_w(
    const float* __restrict__ W, unsigned short* __restrict__ WT) {
  __shared__ float Ls[64][65];
  const int n0 = blockIdx.x * 64;
  const int k0 = blockIdx.y * 64;
  const int c = (threadIdx.x & 15) << 2;
  const int r = threadIdx.x >> 4;
#pragma unroll
  for (int rr = 0; rr < 64; rr += 16) {
    float4 v = *(const float4*)(W + (size_t)(k0 + r + rr) * 3072 + n0 + c);
    Ls[r + rr][c + 0] = v.x; Ls[r + rr][c + 1] = v.y;
    Ls[r + rr][c + 2] = v.z; Ls[r + rr][c + 3] = v.w;
  }
  __syncthreads();
#pragma unroll
  for (int rr = 0; rr < 64; rr += 16) {
    const int X = r + rr;
    ushort4 u;
    u.x = f2bf(Ls[c + 0][X]); u.y = f2bf(Ls[c + 1][X]);
    u.z = f2bf(Ls[c + 2][X]); u.w = f2bf(Ls[c + 3][X]);
    *(ushort4*)(WT + (size_t)(n0 + X) * C_DIM + k0 + c) = u;
  }
}

// ---------------------------------------------------------------------------
// gemm256<MODE>: 256x256-tile, BK=64, 512-thread (8-wave, 2Mx4N) 8-phase
// GEMM with counted vmcnt (T3+T4), LDS XOR-swizzle (T2), setprio (T5).
// K-loop uses RAW s_barrier + counted vmcnt -- no __syncthreads (no vmcnt(0)
// drain). Per K-tile: 4 phases; phase = {ds_read quadrant | stage 1 half-tile
// (2 global_load_lds)} -> BARa -> lgkmcnt(0) -> prio1 -> 16 MFMA -> prio0 ->
// BARb. Waits one phase AHEAD of the reads they protect:
//   phase1: vmcnt(6)  protects phase-2/3 reads (B.C1, A.R1 of this K-tile)
//   phase4: vmcnt(8)  protects next iter's phase-1 reads (A.R0, B.C0)
// Stage slots (2 loads each): p1: A(t+1).grp1  p2: B(t+1).grp1
//                             p3: A(t+2).grp0  p4: B(t+2).grp0
// LDS layout: As[buf][grp][128][64]; A row -> grp=(row>>6)&1. B col ->
// grp=(col>>5)&1. Swizzle: 16B-unit u at row r holds k-unit u^(r&7); global
// source pre-permuted to match (rule #21 both-sides). Conflicts measured 0.
// MODE 4: merged QKV (QK: bf16+bias[col]; V^T: bf16+bias[row])
// MODE 2: S = Q K^T * 1/32, lower-triangle 256-tiles, bf16
// MODE 3: O = P V, causal split-K chunks of 1024, fp32 out (+atomics)
// ---------------------------------------------------------------------------
template <int MODE>
__global__ __launch_bounds__(512) void gemm256(
    const unsigned short* __restrict__ A_, const unsigned short* __restrict__ BT_,
    void* __restrict__ Cv, const float* __restrict__ bias_,
    int lda, int ldb, int ldc, int T) {
  __shared__ __align__(16) unsigned short As[2][2][128][64];  // 64 KB
  __shared__ __align__(16) unsigned short Bs[2][2][128][64];  // 64 KB

  const int tid = threadIdx.x, lane = tid & 63, w = tid >> 6;
  const int wr = w >> 2, wc = w & 3;          // wave grid 2M x 4N
  const int qd = lane >> 4, n16 = lane & 15;

  const unsigned short* A  = A_;
  const unsigned short* BT = BT_;
  const float* bias = bias_;
  unsigned short* Cb = (unsigned short*)Cv;
  float* Cf = (float*)Cv;
  int ldc_ = ldc;
  int m0, n0, kbeg = 0, kend = C_DIM;
  bool use_atomic = false, rowbias = false;

  if (MODE == 4) {
    const int nQKx = QKS >> 8;
    const int nQK  = (T >> 8) * nQKx;
    int id = (int)blockIdx.x;
    if (id < nQK) {                      // Q|K part: xb @ WT^T
      m0 = (id / nQKx) << 8; n0 = (id % nQKx) << 8;
    } else {                             // V^T part: Wv^T @ xb^T
      id -= nQK;
      const int nVx = T >> 8;
      m0 = (id / nVx) << 8; n0 = (id % nVx) << 8;
      A  = BT_ + (size_t)QKS * C_DIM;
      BT = A_;
      Cb = (unsigned short*)Cv + (size_t)T * QKS;   // vtb
      bias = bias_ + QKS; rowbias = true; ldc_ = T;
    }
  } else if (MODE == 2) {
    if ((int)blockIdx.x > (int)blockIdx.y) return;  // upper triangle: skip
    m0 = (int)blockIdx.y << 8; n0 = (int)blockIdx.x << 8;
  } else {  // MODE 3: causal PV, K chunks of 1024
    const int nnx = C_DIM >> 8;
    int id = (int)blockIdx.x;
    const int nx = id % nnx;
    int s = id / nnx;
    int bi = 0;
    while (s >= ((bi >> 2) + 1)) { s -= (bi >> 2) + 1; ++bi; }
    m0 = bi << 8; n0 = nx << 8;
    kbeg = s << 10;
    const int kfull = (bi + 1) << 8;
    kend = kbeg + 1024 < kfull ? kbeg + 1024 : kfull;
    use_atomic = (kfull > 1024);                    // rows >=1024 pre-zeroed
  }

  const int NT = (kend - kbeg) >> 6;    // K-tiles of 64 (>=1)

  // ---- staging source pointers (pre-swizzled global k-unit, rule #21)
  const int l3 = lane >> 3;                       // = (phys LDS row)&7
  const int su = (((lane & 7) ^ l3) << 3);        // swizzled k elem offset
  const unsigned short* asrc[2][2];
  const unsigned short* bsrc[2][2];
#pragma unroll
  for (int g = 0; g < 2; ++g)
#pragma unroll
    for (int c = 0; c < 2; ++c) {
      asrc[g][c] = A  + (size_t)(m0 + c * 128 + g * 64 + (w << 3) + l3) * lda + kbeg + su;
      bsrc[g][c] = BT + (size_t)(n0 + (c * 2 + (w >> 2)) * 64 + g * 32 + ((w & 3) << 3) + l3) * ldb + kbeg + su;
    }

#define STAGE_A(buf, g, kk) do { \
    gload_lds16(asrc[g][0] + (kk), &As[buf][g][(w << 3)][0]);      \
    gload_lds16(asrc[g][1] + (kk), &As[buf][g][64 + (w << 3)][0]); \
  } while (0)
#define STAGE_B(buf, g, kk) do { \
    gload_lds16(bsrc[g][0] + (kk), &Bs[buf][g][(w << 3)][0]);      \
    gload_lds16(bsrc[g][1] + (kk), &Bs[buf][g][64 + (w << 3)][0]); \
  } while (0)

  // ---- fragment read addressing (swizzled)
  const int arow = (wr << 6) + n16;               // + fm*16, grp = mh
  const int brow = (wc << 5) + n16;               // + fn*16, grp = nh
  const int sw0 = ((qd ^ (n16 & 7)) << 3);        // ks=0
  const int sw1 = (((4 + qd) ^ (n16 & 7)) << 3);  // ks=1

#define READ_A(AA, mh, buf) do { \
  _Pragma("unroll") for (int fm = 0; fm < 4; ++fm) { \
    AA[fm][0] = *(const bf16x8*)&As[buf][mh][arow + fm * 16][sw0]; \
    AA[fm][1] = *(const bf16x8*)&As[buf][mh][arow + fm * 16][sw1]; \
  } } while (0)
#define READ_B(BB, g, buf) do { \
  _Pragma("unroll") for (int fn = 0; fn < 2; ++fn) { \
    BB[fn][0] = *(const bf16x8*)&Bs[buf][g][brow + fn * 16][sw0]; \
    BB[fn][1] = *(const bf16x8*)&Bs[buf][g][brow + fn * 16][sw1]; \
  } } while (0)

  f32x4 acc[8][4];
#pragma unroll
  for (int i = 0; i < 8; ++i)
#pragma unroll
    for (int j = 0; j < 4; ++j) acc[i][j] = (f32x4){0.f, 0.f, 0.f, 0.f};

#define MFMA_QUAD(mh, nh, AA, BB) do { \
  _Pragma("unroll") for (int fm = 0; fm < 4; ++fm) \
  _Pragma("unroll") for (int fn = 0; fn < 2; ++fn) { \
    acc[(mh) * 4 + fm][(nh) * 2 + fn] = mfma16(AA[fm][0], BB[fn][0], acc[(mh) * 4 + fm][(nh) * 2 + fn]); \
    acc[(mh) * 4 + fm][(nh) * 2 + fn] = mfma16(AA[fm][1], BB[fn][1], acc[(mh) * 4 + fm][(nh) * 2 + fn]); \
  } } while (0)

  // ---- prologue: K0 all 4 halves, then early halves of K1
  STAGE_A(0, 0, 0); STAGE_B(0, 0, 0);
  STAGE_A(0, 1, 0); STAGE_B(0, 1, 0);
  if (NT > 1) { STAGE_A(1, 0, 64); STAGE_B(1, 0, 64); }
  if (NT > 1) VMCNT(8); else VMCNT(4);   // retire K0.grp0 stages
  SBAR; BARRIER;

  bf16x8 a[4][2], b0[2][2], b1[2][2];
  for (int t = 0; t < NT; ++t) {
    const int p = t & 1, pn = p ^ 1;
    const int knx  = (t + 1) << 6;
    const int knx2 = (t + 2) << 6;
    const bool s1 = (t + 1 < NT), s2 = (t + 2 < NT);

    // ---- phase 1: quadrant (0,0)
    READ_A(a, 0, p); READ_B(b0, 0, p);
    if (s1) STAGE_A(pn, 1, knx);
    if (s1) { VMCNT(6); } else { VMCNT(0); }
    SBAR; BARRIER; LGKMCNT0; SBAR;
    __builtin_amdgcn_s_setprio(1); MFMA_QUAD(0, 0, a, b0); __builtin_amdgcn_s_setprio(0);
    SBAR; BARRIER;
    // ---- phase 2: quadrant (0,1)
    READ_B(b1, 1, p);
    if (s1) STAGE_B(pn, 1, knx);
    SBAR; BARRIER; LGKMCNT0; SBAR;
    __builtin_amdgcn_s_setprio(1); MFMA_QUAD(0, 1, a, b1); __builtin_amdgcn_s_setprio(0);
    SBAR; BARRIER;
    // ---- phase 3: quadrant (1,0)  (reuses b0 regs; reloads a from grp1)
    READ_A(a, 1, p);
    if (s2) STAGE_A(p, 0, knx2);
    SBAR; BARRIER; LGKMCNT0; SBAR;
    __builtin_amdgcn_s_setprio(1); MFMA_QUAD(1, 0, a, b0); __builtin_amdgcn_s_setprio(0);
    SBAR; BARRIER;
    // ---- phase 4: quadrant (1,1)  (no new reads)
    if (s2) STAGE_B(p, 0, knx2);
    if (s1) { if (s2) { VMCNT(8); } else { VMCNT(4); } }
    SBAR; BARRIER;
    __builtin_amdgcn_s_setprio(1); MFMA_QUAD(1, 1, a, b1); __builtin_amdgcn_s_setprio(0);
    SBAR; BARRIER;
  }

  // ---- epilogue. Frag map: col=n16, row=qd*4+r within each 16x16.
  if (MODE == 3) {
#pragma unroll
    for (int fm = 0; fm < 8; ++fm)
#pragma unroll
      for (int fn = 0; fn < 4; ++fn) {
        const int col  = n0 + (wc << 6) + (fn << 4) + n16;
        const int rowb = m0 + (wr << 7) + (fm << 4) + (qd << 2);
#pragma unroll
        for (int r = 0; r < 4; ++r) {
          if (use_atomic) atomicAdd(&Cf[(size_t)(rowb + r) * ldc_ + col], acc[fm][fn][r]);
          else            Cf[(size_t)(rowb + r) * ldc_ + col] = acc[fm][fn][r];
        }
      }
  } else {
#pragma unroll
    for (int fm = 0; fm < 8; ++fm)
#pragma unroll
      for (int fn = 0; fn < 4; ++fn) {
        const int col  = n0 + (wc << 6) + (fn << 4) + n16;
        const int rowb = m0 + (wr << 7) + (fm << 4) + (qd << 2);
        const float bc = (MODE == 4 && !rowbias) ? bias[col] : 0.f;
#pragma unroll
        for (int r = 0; r < 4; ++r) {
          float v = acc[fm][fn][r];
          if (MODE == 4) v += rowbias ? bias[rowb + r] : bc;
          if (MODE == 2) v *= 0.03125f;
          Cb[(size_t)(rowb + r) * ldc_ + col] = f2bf(v);
        }
      }
  }
#undef STAGE_A
#undef STAGE_B
#undef READ_A
#undef READ_B
#undef MFMA_QUAD
}

// ---------------------------------------------------------------------------
// softmax_rows: in-place row softmax on S -> P (bf16), causal+padding masked,
// normalized. Rows < n_padd -> zeros (fixed up later). Each row writes keys
// [0, ceil256(i+1)) so PV's 256-wide tile K-loop reads 0s above the diagonal.
// Also grid-strides a zero-fill of out rows [1024, T) (PV atomic targets) --
// folded from the former zero_hi dispatch; completes before PV launches.
// ---------------------------------------------------------------------------
__global__ __launch_bounds__(256) void softmax_rows(
    unsigned short* __restrict__ P, const int* __restrict__ np_p, int T,
    float* __restrict__ out) {
  __shared__ float red[8];
  // folded zero_hi: out rows [1024, T)
  {
    const int nz4 = ((T - 1024) * C_DIM) >> 2;
    const int gidx = (int)blockIdx.x * 256 + threadIdx.x;
    const int stride = (int)gridDim.x * 256;
    const float4 z4 = {0.f, 0.f, 0.f, 0.f};
    for (int i = gidx; i < nz4; i += stride)
      *(float4*)(out + (size_t)1024 * C_DIM + ((size_t)i << 2)) = z4;
  }
  const int i = blockIdx.x;
  const int np = *np_p;
  const int klen = ((i >> 8) + 1) << 8;     // 256-tile boundary for PV
  const int tid = threadIdx.x, lane = tid & 63, w = tid >> 6;
  const int j0 = tid << 4;
  unsigned short* rowp = P + (size_t)i * T;
  const bool act = j0 < klen;

  if (i < np) {
    if (act) {
      uint4 z = {0, 0, 0, 0};
      *(uint4*)(rowp + j0) = z;
      *(uint4*)(rowp + j0 + 8) = z;
    }
    return;
  }

  float v[16];
  float mx = -3.0e38f;
  if (act) {
    uint4 u0 = *(const uint4*)(rowp + j0);
    uint4 u1 = *(const uint4*)(rowp + j0 + 8);
    const unsigned int uu[8] = {u0.x, u0.y, u0.z, u0.w, u1.x, u1.y, u1.z, u1.w};
#pragma unroll
    for (int u = 0; u < 8; ++u) {
      v[2 * u]     = bf2f(uu[u] & 0xffff);
      v[2 * u + 1] = bf2f(uu[u] >> 16);
    }
#pragma unroll
    for (int u = 0; u < 16; ++u) {
      const int j = j0 + u;
      if (j > i || j < np) v[u] = -3.0e38f;
      mx = fmaxf(mx, v[u]);
    }
  }
  mx = fmaxf(mx, __shfl_xor(mx, 32));
  mx = fmaxf(mx, __shfl_xor(mx, 16));
  mx = fmaxf(mx, __shfl_xor(mx, 8));
  mx = fmaxf(mx, __shfl_xor(mx, 4));
  mx = fmaxf(mx, __shfl_xor(mx, 2));
  mx = fmaxf(mx, __shfl_xor(mx, 1));
  if (lane == 0) red[w] = mx;
  __syncthreads();
  const float M = fmaxf(fmaxf(red[0], red[1]), fmaxf(red[2], red[3]));

  float sum = 0.f;
  if (act) {
#pragma unroll
    for (int u = 0; u < 16; ++u) {
      const float p = (v[u] > -1.0e30f) ? __expf(v[u] - M) : 0.f;
      v[u] = p;
      sum += p;
    }
  }
  sum += __shfl_xor(sum, 32);
  sum += __shfl_xor(sum, 16);
  sum += __shfl_xor(sum, 8);
  sum += __shfl_xor(sum, 4);
  sum += __shfl_xor(sum, 2);
  sum += __shfl_xor(sum, 1);
  if (lane == 0) red[4 + w] = sum;
  __syncthreads();
  const float inv = 1.0f / (red[4] + red[5] + red[6] + red[7]);

  if (act) {
    unsigned int o[8];
#pragma unroll
    for (int u = 0; u < 8; ++u) {
      const unsigned int lo = f2bf(v[2 * u] * inv);
      const unsigned int hi = f2bf(v[2 * u + 1] * inv);
      o[u] = lo | (hi << 16);
    }
    uint4 s0 = {o[0], o[1], o[2], o[3]};
    uint4 s1 = {o[4], o[5], o[6], o[7]};
    *(uint4*)(rowp + j0) = s0;
    *(uint4*)(rowp + j0 + 8) = s1;
  }
}

// ---------------------------------------------------------------------------
// padfix: rows < n_padd get uniform attention over ALL T keys (mean of V)
// ---------------------------------------------------------------------------
__global__ __launch_bounds__(256) void padfix(
    const unsigned short* __restrict__ vtb, const int* __restrict__ np_p,
    float* __restrict__ out, int T) {
  const int np = *np_p;
  const int row0 = blockIdx.x * 32;
  if (row0 >= np) return;
  const int pc = min(np - row0, 32);
  const int c4 = threadIdx.x << 2;
  float a[4] = {0.f, 0.f, 0.f, 0.f};
#pragma unroll
  for (int c = 0; c < 4; ++c) {
    const unsigned short* vr = vtb + (size_t)(c4 + c) * T;
    for (int j = 0; j < T; j += 8) {
      uint4 v = *(const uint4*)(vr + j);
      a[c] += bf2f(v.x & 0xffff) + bf2f(v.x >> 16) + bf2f(v.y & 0xffff) + bf2f(v.y >> 16)
            + bf2f(v.z & 0xffff) + bf2f(v.z >> 16) + bf2f(v.w & 0xffff) + bf2f(v.w >> 16);
    }
  }
  const float inv = 1.0f / (float)T;
  float4 rv = {a[0] * inv, a[1] * inv, a[2] * inv, a[3] * inv};
  for (int r = 0; r < pc; ++r)
    *(float4*)(out + (size_t)(row0 + r) * C_DIM + c4) = rv;
}

// ---------------------------------------------------------------------------
extern "C" void kernel_launch(void* const* d_in, const int* in_sizes, int n_in,
                              void* d_out, int out_size, void* d_ws, size_t ws_size,
                              hipStream_t stream) {
  const float* x    = (const float*)d_in[0];
  const float* W    = (const float*)d_in[1];
  const float* b    = (const float*)d_in[2];
  const int* n_padd = (const int*)d_in[3];
  float* out = (float*)d_out;

  const int T = in_sizes[0] / C_DIM;
  // ws layout (overlapping lifetimes):
  //   [0,16M)  qkb [T][2048] bf16   (Q|K, persistent until PV)
  //   [16,24M) vtb [1024][T] bf16   (V^T, persistent)
  //   [24M..)  phase1: xb [T][1024] (8M) + WT [3072][1024] (6M)
  //            phase2: P  [T][T] bf16 (33.5M) overlays xb/WT
  unsigned short* qkb = (unsigned short*)d_ws;
  unsigned short* vtb = qkb + (size_t)T * QKS;
  unsigned short* xb  = vtb + (size_t)C_DIM * T;
  unsigned short* WT  = xb  + (size_t)T * C_DIM;
  unsigned short* P   = xb;

  cast_x<<<(T * C_DIM) / 1024, 256, 0, stream>>>(x, xb);
  transpose_w<<<dim3(48, 16), 256, 0, stream>>>(W, WT);

  // Merged QKV: blocks [0,nQK) -> Q|K, rest -> V^T (vtb = Cv + T*QKS)
  {
    const int nQK = (T >> 8) * (QKS >> 8);
    const int nV  = (C_DIM >> 8) * (T >> 8);
    gemm256<4><<<nQK + nV, 512, 0, stream>>>(
        xb, WT, qkb, b, C_DIM, C_DIM, QKS, T);
  }
  // S = Q @ K^T * 1/32  (lower-triangle 256-tiles), bf16 [T][T]
  gemm256<2><<<dim3(T >> 8, T >> 8), 512, 0, stream>>>(
      qkb, qkb + C_DIM, P, b, QKS, QKS, T, T);
  // P = softmax(S) (normalized, masked, 256-col zero-fill) + zero out[1024:]
  softmax_rows<<<T, 256, 0, stream>>>(P, n_padd, T, out);
  // O = P @ V (causal split-K chunks of 1024)
  {
    const int nyt = T >> 8;
    int slots = 0;
    for (int bi = 0; bi < nyt; ++bi) slots += (bi >> 2) + 1;
    gemm256<3><<<slots * (C_DIM >> 8), 512, 0, stream>>>(
        P, vtb, out, b, T, T, C_DIM, T);
  }
  padfix<<<T / 32, 256, 0, stream>>>(vtb, n_padd, out, T);
}

// Round 11
// 219.705 us; speedup vs baseline: 3.6435x; 1.0099x over previous
//
#include <hip/hip_runtime.h>
#include <hip/hip_bf16.h>
#include <math.h>

#define C_DIM 1024
#define QKS  2048    // Q|K row stride in bf16 workspace

typedef __attribute__((ext_vector_type(8))) short bf16x8;   // 8 bf16 = 4 VGPRs
typedef __attribute__((ext_vector_type(4))) float f32x4;    // MFMA C/D

__device__ __forceinline__ unsigned short f2bf(float f) {
  __hip_bfloat16 h = __float2bfloat16(f);
  return *(reinterpret_cast<unsigned short*>(&h));
}
__device__ __forceinline__ float bf2f(unsigned short u) {
  return __uint_as_float(((unsigned int)u) << 16);
}
__device__ __forceinline__ f32x4 mfma16(bf16x8 a, bf16x8 b, f32x4 c) {
  return __builtin_amdgcn_mfma_f32_16x16x32_bf16(a, b, c, 0, 0, 0);
}
__device__ __forceinline__ void gload_lds16(const unsigned short* g,
                                            unsigned short* l) {
  __builtin_amdgcn_global_load_lds(
      (const __attribute__((address_space(1))) void*)(g),
      (__attribute__((address_space(3))) void*)(l), 16, 0, 0);
}

#define VMCNT(n)  asm volatile("s_waitcnt vmcnt(" #n ")" ::: "memory")
#define LGKMCNT0  asm volatile("s_waitcnt lgkmcnt(0)" ::: "memory")
#define SBAR      __builtin_amdgcn_sched_barrier(0)
#define BARRIER   __builtin_amdgcn_s_barrier()

// ---------------------------------------------------------------------------
// prep: merged {cast x fp32 -> xb bf16} + {W [1024][3072] fp32 -> WT
// [3072][1024] bf16 transpose}. Blocks [0,nc): cast; blocks [nc,nc+768):
// one 64x64 transpose tile each. (Verified structure from R8.)
// ---------------------------------------------------------------------------
__global__ __launch_bounds__(256) void prep(
    const float* __restrict__ x, const float* __restrict__ W,
    unsigned short* __restrict__ xb, unsigned short* __restrict__ WT, int nc) {
  __shared__ float Ls[64][65];
  const int id = (int)blockIdx.x;
  if (id < nc) {
    const int i = (id * 256 + threadIdx.x) << 2;
    float4 v = *(const float4*)(x + i);
    ushort4 u;
    u.x = f2bf(v.x); u.y = f2bf(v.y); u.z = f2bf(v.z); u.w = f2bf(v.w);
    *(ushort4*)(xb + i) = u;
    return;
  }
  const int id2 = id - nc;
  const int n0 = (id2 % 48) * 64;
  const int k0 = (id2 / 48) * 64;
  const int c = (threadIdx.x & 15) << 2;
  const int r = threadIdx.x >> 4;
#pragma unroll
  for (int rr = 0; rr < 64; rr += 16) {
    float4 v = *(const float4*)(W + (size_t)(k0 + r + rr) * 3072 + n0 + c);
    Ls[r + rr][c + 0] = v.x; Ls[r + rr][c + 1] = v.y;
    Ls[r + rr][c + 2] = v.z; Ls[r + rr][c + 3] = v.w;
  }
  __syncthreads();
#pragma unroll
  for (int rr = 0; rr < 64; rr += 16) {
    const int X = r + rr;
    ushort4 u;
    u.x = f2bf(Ls[c + 0][X]); u.y = f2bf(Ls[c + 1][X]);
    u.z = f2bf(Ls[c + 2][X]); u.w = f2bf(Ls[c + 3][X]);
    *(ushort4*)(WT + (size_t)(n0 + X) * C_DIM + k0 + c) = u;
  }
}

// ---------------------------------------------------------------------------
// gemm256<MODE>: 256x256-tile, BK=64, 512-thread (8-wave, 2Mx4N) 8-phase
// GEMM with counted vmcnt (T3+T4), LDS XOR-swizzle (T2), setprio (T5).
// K-loop uses RAW s_barrier + counted vmcnt -- no __syncthreads (no vmcnt(0)
// drain). Per K-tile: 4 phases; phase = {ds_read quadrant | stage 1 half-tile
// (2 global_load_lds)} -> BARa -> lgkmcnt(0) -> prio1 -> 16 MFMA -> prio0 ->
// BARb. Waits one phase AHEAD of the reads they protect:
//   phase1: vmcnt(6)  protects phase-2/3 reads (B.C1, A.R1 of this K-tile)
//   phase4: vmcnt(8)  protects next iter's phase-1 reads (A.R0, B.C0)
// Stage slots (2 loads each): p1: A(t+1).grp1  p2: B(t+1).grp1
//                             p3: A(t+2).grp0  p4: B(t+2).grp0
// LDS layout: As[buf][grp][128][64]; A row -> grp=(row>>6)&1. B col ->
// grp=(col>>5)&1. Swizzle: 16B-unit u at row r holds k-unit u^(r&7); global
// source pre-permuted to match (rule #21 both-sides). Conflicts measured 0.
// MODE 4: merged QKV (QK: bf16+bias[col]; V^T: bf16+bias[row])
// MODE 2: S = Q K^T * 1/32, lower-triangle 256-tiles, bf16
// MODE 3: O = P V, causal split-K chunks of 1024, fp32 out (+atomics)
// ---------------------------------------------------------------------------
template <int MODE>
__global__ __launch_bounds__(512) void gemm256(
    const unsigned short* __restrict__ A_, const unsigned short* __restrict__ BT_,
    void* __restrict__ Cv, const float* __restrict__ bias_,
    int lda, int ldb, int ldc, int T) {
  __shared__ __align__(16) unsigned short As[2][2][128][64];  // 64 KB
  __shared__ __align__(16) unsigned short Bs[2][2][128][64];  // 64 KB

  const int tid = threadIdx.x, lane = tid & 63, w = tid >> 6;
  const int wr = w >> 2, wc = w & 3;          // wave grid 2M x 4N
  const int qd = lane >> 4, n16 = lane & 15;

  const unsigned short* A  = A_;
  const unsigned short* BT = BT_;
  const float* bias = bias_;
  unsigned short* Cb = (unsigned short*)Cv;
  float* Cf = (float*)Cv;
  int ldc_ = ldc;
  int m0, n0, kbeg = 0, kend = C_DIM;
  bool use_atomic = false, rowbias = false;

  if (MODE == 4) {
    const int nQKx = QKS >> 8;
    const int nQK  = (T >> 8) * nQKx;
    int id = (int)blockIdx.x;
    if (id < nQK) {                      // Q|K part: xb @ WT^T
      m0 = (id / nQKx) << 8; n0 = (id % nQKx) << 8;
    } else {                             // V^T part: Wv^T @ xb^T
      id -= nQK;
      const int nVx = T >> 8;
      m0 = (id / nVx) << 8; n0 = (id % nVx) << 8;
      A  = BT_ + (size_t)QKS * C_DIM;
      BT = A_;
      Cb = (unsigned short*)Cv + (size_t)T * QKS;   // vtb
      bias = bias_ + QKS; rowbias = true; ldc_ = T;
    }
  } else if (MODE == 2) {
    if ((int)blockIdx.x > (int)blockIdx.y) return;  // upper triangle: skip
    m0 = (int)blockIdx.y << 8; n0 = (int)blockIdx.x << 8;
  } else {  // MODE 3: causal PV, K chunks of 1024
    const int nnx = C_DIM >> 8;
    int id = (int)blockIdx.x;
    const int nx = id % nnx;
    int s = id / nnx;
    int bi = 0;
    while (s >= ((bi >> 2) + 1)) { s -= (bi >> 2) + 1; ++bi; }
    m0 = bi << 8; n0 = nx << 8;
    kbeg = s << 10;
    const int kfull = (bi + 1) << 8;
    kend = kbeg + 1024 < kfull ? kbeg + 1024 : kfull;
    use_atomic = (kfull > 1024);                    // rows >=1024 pre-zeroed
  }

  const int NT = (kend - kbeg) >> 6;    // K-tiles of 64 (>=1)

  // ---- staging source pointers (pre-swizzled global k-unit, rule #21)
  const int l3 = lane >> 3;                       // = (phys LDS row)&7
  const int su = (((lane & 7) ^ l3) << 3);        // swizzled k elem offset
  const unsigned short* asrc[2][2];
  const unsigned short* bsrc[2][2];
#pragma unroll
  for (int g = 0; g < 2; ++g)
#pragma unroll
    for (int c = 0; c < 2; ++c) {
      asrc[g][c] = A  + (size_t)(m0 + c * 128 + g * 64 + (w << 3) + l3) * lda + kbeg + su;
      bsrc[g][c] = BT + (size_t)(n0 + (c * 2 + (w >> 2)) * 64 + g * 32 + ((w & 3) << 3) + l3) * ldb + kbeg + su;
    }

#define STAGE_A(buf, g, kk) do { \
    gload_lds16(asrc[g][0] + (kk), &As[buf][g][(w << 3)][0]);      \
    gload_lds16(asrc[g][1] + (kk), &As[buf][g][64 + (w << 3)][0]); \
  } while (0)
#define STAGE_B(buf, g, kk) do { \
    gload_lds16(bsrc[g][0] + (kk), &Bs[buf][g][(w << 3)][0]);      \
    gload_lds16(bsrc[g][1] + (kk), &Bs[buf][g][64 + (w << 3)][0]); \
  } while (0)

  // ---- fragment read addressing (swizzled)
  const int arow = (wr << 6) + n16;               // + fm*16, grp = mh
  const int brow = (wc << 5) + n16;               // + fn*16, grp = nh
  const int sw0 = ((qd ^ (n16 & 7)) << 3);        // ks=0
  const int sw1 = (((4 + qd) ^ (n16 & 7)) << 3);  // ks=1

#define READ_A(AA, mh, buf) do { \
  _Pragma("unroll") for (int fm = 0; fm < 4; ++fm) { \
    AA[fm][0] = *(const bf16x8*)&As[buf][mh][arow + fm * 16][sw0]; \
    AA[fm][1] = *(const bf16x8*)&As[buf][mh][arow + fm * 16][sw1]; \
  } } while (0)
#define READ_B(BB, g, buf) do { \
  _Pragma("unroll") for (int fn = 0; fn < 2; ++fn) { \
    BB[fn][0] = *(const bf16x8*)&Bs[buf][g][brow + fn * 16][sw0]; \
    BB[fn][1] = *(const bf16x8*)&Bs[buf][g][brow + fn * 16][sw1]; \
  } } while (0)

  f32x4 acc[8][4];
#pragma unroll
  for (int i = 0; i < 8; ++i)
#pragma unroll
    for (int j = 0; j < 4; ++j) acc[i][j] = (f32x4){0.f, 0.f, 0.f, 0.f};

#define MFMA_QUAD(mh, nh, AA, BB) do { \
  _Pragma("unroll") for (int fm = 0; fm < 4; ++fm) \
  _Pragma("unroll") for (int fn = 0; fn < 2; ++fn) { \
    acc[(mh) * 4 + fm][(nh) * 2 + fn] = mfma16(AA[fm][0], BB[fn][0], acc[(mh) * 4 + fm][(nh) * 2 + fn]); \
    acc[(mh) * 4 + fm][(nh) * 2 + fn] = mfma16(AA[fm][1], BB[fn][1], acc[(mh) * 4 + fm][(nh) * 2 + fn]); \
  } } while (0)

  // ---- prologue: K0 all 4 halves, then early halves of K1
  STAGE_A(0, 0, 0); STAGE_B(0, 0, 0);
  STAGE_A(0, 1, 0); STAGE_B(0, 1, 0);
  if (NT > 1) { STAGE_A(1, 0, 64); STAGE_B(1, 0, 64); }
  if (NT > 1) VMCNT(8); else VMCNT(4);   // retire K0.grp0 stages
  SBAR; BARRIER;

  bf16x8 a[4][2], b0[2][2], b1[2][2];
  for (int t = 0; t < NT; ++t) {
    const int p = t & 1, pn = p ^ 1;
    const int knx  = (t + 1) << 6;
    const int knx2 = (t + 2) << 6;
    const bool s1 = (t + 1 < NT), s2 = (t + 2 < NT);

    // ---- phase 1: quadrant (0,0)
    READ_A(a, 0, p); READ_B(b0, 0, p);
    if (s1) STAGE_A(pn, 1, knx);
    if (s1) { VMCNT(6); } else { VMCNT(0); }
    SBAR; BARRIER; LGKMCNT0; SBAR;
    __builtin_amdgcn_s_setprio(1); MFMA_QUAD(0, 0, a, b0); __builtin_amdgcn_s_setprio(0);
    SBAR; BARRIER;
    // ---- phase 2: quadrant (0,1)
    READ_B(b1, 1, p);
    if (s1) STAGE_B(pn, 1, knx);
    SBAR; BARRIER; LGKMCNT0; SBAR;
    __builtin_amdgcn_s_setprio(1); MFMA_QUAD(0, 1, a, b1); __builtin_amdgcn_s_setprio(0);
    SBAR; BARRIER;
    // ---- phase 3: quadrant (1,0)  (reuses b0 regs; reloads a from grp1)
    READ_A(a, 1, p);
    if (s2) STAGE_A(p, 0, knx2);
    SBAR; BARRIER; LGKMCNT0; SBAR;
    __builtin_amdgcn_s_setprio(1); MFMA_QUAD(1, 0, a, b0); __builtin_amdgcn_s_setprio(0);
    SBAR; BARRIER;
    // ---- phase 4: quadrant (1,1)  (no new reads)
    if (s2) STAGE_B(p, 0, knx2);
    if (s1) { if (s2) { VMCNT(8); } else { VMCNT(4); } }
    SBAR; BARRIER;
    __builtin_amdgcn_s_setprio(1); MFMA_QUAD(1, 1, a, b1); __builtin_amdgcn_s_setprio(0);
    SBAR; BARRIER;
  }

  // ---- epilogue. Frag map: col=n16, row=qd*4+r within each 16x16.
  if (MODE == 3) {
#pragma unroll
    for (int fm = 0; fm < 8; ++fm)
#pragma unroll
      for (int fn = 0; fn < 4; ++fn) {
        const int col  = n0 + (wc << 6) + (fn << 4) + n16;
        const int rowb = m0 + (wr << 7) + (fm << 4) + (qd << 2);
#pragma unroll
        for (int r = 0; r < 4; ++r) {
          if (use_atomic) atomicAdd(&Cf[(size_t)(rowb + r) * ldc_ + col], acc[fm][fn][r]);
          else            Cf[(size_t)(rowb + r) * ldc_ + col] = acc[fm][fn][r];
        }
      }
  } else {
#pragma unroll
    for (int fm = 0; fm < 8; ++fm)
#pragma unroll
      for (int fn = 0; fn < 4; ++fn) {
        const int col  = n0 + (wc << 6) + (fn << 4) + n16;
        const int rowb = m0 + (wr << 7) + (fm << 4) + (qd << 2);
        const float bc = (MODE == 4 && !rowbias) ? bias[col] : 0.f;
#pragma unroll
        for (int r = 0; r < 4; ++r) {
          float v = acc[fm][fn][r];
          if (MODE == 4) v += rowbias ? bias[rowb + r] : bc;
          if (MODE == 2) v *= 0.03125f;
          Cb[(size_t)(rowb + r) * ldc_ + col] = f2bf(v);
        }
      }
  }
#undef STAGE_A
#undef STAGE_B
#undef READ_A
#undef READ_B
#undef MFMA_QUAD
}

// ---------------------------------------------------------------------------
// softmax_rows: in-place row softmax on S -> P (bf16), causal+padding masked,
// normalized. Rows < n_padd -> zeros (fixed up later). Each row writes keys
// [0, ceil256(i+1)) so PV's 256-wide tile K-loop reads 0s above the diagonal.
// Also grid-strides a zero-fill of out rows [1024, T) (PV atomic targets) --
// folded zero_hi; completes before PV launches (same stream).
// ---------------------------------------------------------------------------
__global__ __launch_bounds__(256) void softmax_rows(
    unsigned short* __restrict__ P, const int* __restrict__ np_p, int T,
    float* __restrict__ out) {
  __shared__ float red[8];
  // folded zero_hi: out rows [1024, T)
  {
    const int nz4 = ((T - 1024) * C_DIM) >> 2;
    const int gidx = (int)blockIdx.x * 256 + threadIdx.x;
    const int stride = (int)gridDim.x * 256;
    const float4 z4 = {0.f, 0.f, 0.f, 0.f};
    for (int i = gidx; i < nz4; i += stride)
      *(float4*)(out + (size_t)1024 * C_DIM + ((size_t)i << 2)) = z4;
  }
  const int i = blockIdx.x;
  const int np = *np_p;
  const int klen = ((i >> 8) + 1) << 8;     // 256-tile boundary for PV
  const int tid = threadIdx.x, lane = tid & 63, w = tid >> 6;
  const int j0 = tid << 4;
  unsigned short* rowp = P + (size_t)i * T;
  const bool act = j0 < klen;

  if (i < np) {
    if (act) {
      uint4 z = {0, 0, 0, 0};
      *(uint4*)(rowp + j0) = z;
      *(uint4*)(rowp + j0 + 8) = z;
    }
    return;
  }

  float v[16];
  float mx = -3.0e38f;
  if (act) {
    uint4 u0 = *(const uint4*)(rowp + j0);
    uint4 u1 = *(const uint4*)(rowp + j0 + 8);
    const unsigned int uu[8] = {u0.x, u0.y, u0.z, u0.w, u1.x, u1.y, u1.z, u1.w};
#pragma unroll
    for (int u = 0; u < 8; ++u) {
      v[2 * u]     = bf2f(uu[u] & 0xffff);
      v[2 * u + 1] = bf2f(uu[u] >> 16);
    }
#pragma unroll
    for (int u = 0; u < 16; ++u) {
      const int j = j0 + u;
      if (j > i || j < np) v[u] = -3.0e38f;
      mx = fmaxf(mx, v[u]);
    }
  }
  mx = fmaxf(mx, __shfl_xor(mx, 32));
  mx = fmaxf(mx, __shfl_xor(mx, 16));
  mx = fmaxf(mx, __shfl_xor(mx, 8));
  mx = fmaxf(mx, __shfl_xor(mx, 4));
  mx = fmaxf(mx, __shfl_xor(mx, 2));
  mx = fmaxf(mx, __shfl_xor(mx, 1));
  if (lane == 0) red[w] = mx;
  __syncthreads();
  const float M = fmaxf(fmaxf(red[0], red[1]), fmaxf(red[2], red[3]));

  float sum = 0.f;
  if (act) {
#pragma unroll
    for (int u = 0; u < 16; ++u) {
      const float p = (v[u] > -1.0e30f) ? __expf(v[u] - M) : 0.f;
      v[u] = p;
      sum += p;
    }
  }
  sum += __shfl_xor(sum, 32);
  sum += __shfl_xor(sum, 16);
  sum += __shfl_xor(sum, 8);
  sum += __shfl_xor(sum, 4);
  sum += __shfl_xor(sum, 2);
  sum += __shfl_xor(sum, 1);
  if (lane == 0) red[4 + w] = sum;
  __syncthreads();
  const float inv = 1.0f / (red[4] + red[5] + red[6] + red[7]);

  if (act) {
    unsigned int o[8];
#pragma unroll
    for (int u = 0; u < 8; ++u) {
      const unsigned int lo = f2bf(v[2 * u] * inv);
      const unsigned int hi = f2bf(v[2 * u + 1] * inv);
      o[u] = lo | (hi << 16);
    }
    uint4 s0 = {o[0], o[1], o[2], o[3]};
    uint4 s1 = {o[4], o[5], o[6], o[7]};
    *(uint4*)(rowp + j0) = s0;
    *(uint4*)(rowp + j0 + 8) = s1;
  }
}

// ---------------------------------------------------------------------------
// padfix: rows < n_padd get uniform attention over ALL T keys (mean of V)
// ---------------------------------------------------------------------------
__global__ __launch_bounds__(256) void padfix(
    const unsigned short* __restrict__ vtb, const int* __restrict__ np_p,
    float* __restrict__ out, int T) {
  const int np = *np_p;
  const int row0 = blockIdx.x * 32;
  if (row0 >= np) return;
  const int pc = min(np - row0, 32);
  const int c4 = threadIdx.x << 2;
  float a[4] = {0.f, 0.f, 0.f, 0.f};
#pragma unroll
  for (int c = 0; c < 4; ++c) {
    const unsigned short* vr = vtb + (size_t)(c4 + c) * T;
    for (int j = 0; j < T; j += 8) {
      uint4 v = *(const uint4*)(vr + j);
      a[c] += bf2f(v.x & 0xffff) + bf2f(v.x >> 16) + bf2f(v.y & 0xffff) + bf2f(v.y >> 16)
            + bf2f(v.z & 0xffff) + bf2f(v.z >> 16) + bf2f(v.w & 0xffff) + bf2f(v.w >> 16);
    }
  }
  const float inv = 1.0f / (float)T;
  float4 rv = {a[0] * inv, a[1] * inv, a[2] * inv, a[3] * inv};
  for (int r = 0; r < pc; ++r)
    *(float4*)(out + (size_t)(row0 + r) * C_DIM + c4) = rv;
}

// ---------------------------------------------------------------------------
extern "C" void kernel_launch(void* const* d_in, const int* in_sizes, int n_in,
                              void* d_out, int out_size, void* d_ws, size_t ws_size,
                              hipStream_t stream) {
  const float* x    = (const float*)d_in[0];
  const float* W    = (const float*)d_in[1];
  const float* b    = (const float*)d_in[2];
  const int* n_padd = (const int*)d_in[3];
  float* out = (float*)d_out;

  const int T = in_sizes[0] / C_DIM;
  // ws layout (overlapping lifetimes):
  //   [0,16M)  qkb [T][2048] bf16   (Q|K, persistent until PV)
  //   [16,24M) vtb [1024][T] bf16   (V^T, persistent)
  //   [24M..)  phase1: xb [T][1024] (8M) + WT [3072][1024] (6M)
  //            phase2: P  [T][T] bf16 (33.5M) overlays xb/WT
  unsigned short* qkb = (unsigned short*)d_ws;
  unsigned short* vtb = qkb + (size_t)T * QKS;
  unsigned short* xb  = vtb + (size_t)C_DIM * T;
  unsigned short* WT  = xb  + (size_t)T * C_DIM;
  unsigned short* P   = xb;

  // merged cast + transpose
  const int nc = (T * C_DIM) >> 10;
  prep<<<nc + 768, 256, 0, stream>>>(x, W, xb, WT, nc);

  // Merged QKV: blocks [0,nQK) -> Q|K, rest -> V^T (vtb = Cv + T*QKS)
  {
    const int nQK = (T >> 8) * (QKS >> 8);
    const int nV  = (C_DIM >> 8) * (T >> 8);
    gemm256<4><<<nQK + nV, 512, 0, stream>>>(
        xb, WT, qkb, b, C_DIM, C_DIM, QKS, T);
  }
  // S = Q @ K^T * 1/32  (lower-triangle 256-tiles), bf16 [T][T]
  gemm256<2><<<dim3(T >> 8, T >> 8), 512, 0, stream>>>(
      qkb, qkb + C_DIM, P, b, QKS, QKS, T, T);
  // P = softmax(S) (normalized, masked, 256-col zero-fill) + zero out[1024:]
  softmax_rows<<<T, 256, 0, stream>>>(P, n_padd, T, out);
  // O = P @ V (causal split-K chunks of 1024)
  {
    const int nyt = T >> 8;
    int slots = 0;
    for (int bi = 0; bi < nyt; ++bi) slots += (bi >> 2) + 1;
    gemm256<3><<<slots * (C_DIM >> 8), 512, 0, stream>>>(
        P, vtb, out, b, T, T, C_DIM, T);
  }
  padfix<<<T / 32, 256, 0, stream>>>(vtb, n_padd, out, T);
}